// Round 2
// baseline (263.751 us; speedup 1.0000x reference)
//
#include <hip/hip_runtime.h>

// Problem constants (B=1)
#define NQ   512
#define NKV  2562
#define CH   64
#define QB   2          // queries per block

// ---------------------------------------------------------------------------
// Kernel A: q_ = q @ Wq   [512,64],  kv_ = kv @ Wkv  [2562,128]
// One thread per output element; weights tiny and L2-resident.
// ---------------------------------------------------------------------------
__global__ __launch_bounds__(256) void gemm_qkv(
    const float* __restrict__ q, const float* __restrict__ kv,
    const float* __restrict__ Wq, const float* __restrict__ Wkv,
    float* __restrict__ qp, float* __restrict__ kvp) {
  int t = blockIdx.x * 256 + threadIdx.x;
  const int NQC = NQ * CH;          // 32768
  const int NKV2C = NKV * 2 * CH;   // 327936
  if (t < NQC) {
    int i = t >> 6, c = t & 63;
    const float* qrow = q + i * CH;
    float s = 0.f;
#pragma unroll
    for (int r = 0; r < CH; ++r) s = fmaf(qrow[r], Wq[r * CH + c], s);
    qp[t] = s;
  } else if (t < NQC + NKV2C) {
    int u = t - NQC;
    int n = u >> 7, m = u & 127;
    const float* kvrow = kv + n * CH;
    float s = 0.f;
#pragma unroll
    for (int r = 0; r < CH; ++r) s = fmaf(kvrow[r], Wkv[r * 2 * CH + m], s);
    kvp[u] = s;
  }
}

// ---------------------------------------------------------------------------
// Kernel B: each block handles QB=2 query rows (i0, i0+1), 256 threads.
//   score[j] = ( sum_c exp(-|q_[i,c]-k[j,c]|)
//              + sum_d exp(-|qc[i,d]-kc[j,d]|)*wdsum[d] ) / 64
//   softmax over j; out[c] = sum_j p_j v[j,c]; then out @ Wproj + bproj.
// kv_ layout: row j has k in cols [0,64), v in cols [64,128).
// Each k4/v load from L2 is reused for both queries -> halves L2 traffic.
// ---------------------------------------------------------------------------
__global__ __launch_bounds__(256) void attn_kernel(
    const float* __restrict__ qp, const float* __restrict__ kvp,
    const float* __restrict__ qc, const float* __restrict__ kvc,
    const float* __restrict__ Wdelta, const float* __restrict__ Wproj,
    const float* __restrict__ bproj, float* __restrict__ out) {
  __shared__ float s_score[QB][NKV];   // 20496 B
  __shared__ float s_q[QB][CH];
  __shared__ float s_qc[QB][3];
  __shared__ float s_wd[3];
  __shared__ float s_red[QB][256];
  __shared__ float s_out[QB][CH];

  const int i0 = blockIdx.x * QB;
  const int tid = threadIdx.x;

  if (tid < CH) {
    s_q[0][tid] = qp[i0 * CH + tid];
    s_q[1][tid] = qp[(i0 + 1) * CH + tid];
  }
  if (tid >= 64 && tid < 64 + 3 * QB) {
    int u = tid - 64;                       // u in [0,6)
    s_qc[u / 3][u % 3] = qc[(i0 + u / 3) * 3 + (u % 3)];
  }
  if (tid >= 128 && tid < 131) {
    int d = tid - 128;
    float s = 0.f;
    for (int c = 0; c < CH; ++c) s += Wdelta[d * CH + c];
    s_wd[d] = s;
  }
  __syncthreads();

  const float scale = 1.0f / 64.0f;

  // ---- phase 1: scores for both queries ----
  float lmax0 = -1e30f, lmax1 = -1e30f;
  for (int j = tid; j < NKV; j += 256) {
    const float4* krow = reinterpret_cast<const float4*>(kvp + (size_t)j * 128);
    float s0 = 0.f, s1 = 0.f;
#pragma unroll
    for (int cc = 0; cc < 16; ++cc) {
      float4 k4 = krow[cc];
      s0 += __expf(-fabsf(s_q[0][cc * 4 + 0] - k4.x));
      s0 += __expf(-fabsf(s_q[0][cc * 4 + 1] - k4.y));
      s0 += __expf(-fabsf(s_q[0][cc * 4 + 2] - k4.z));
      s0 += __expf(-fabsf(s_q[0][cc * 4 + 3] - k4.w));
      s1 += __expf(-fabsf(s_q[1][cc * 4 + 0] - k4.x));
      s1 += __expf(-fabsf(s_q[1][cc * 4 + 1] - k4.y));
      s1 += __expf(-fabsf(s_q[1][cc * 4 + 2] - k4.z));
      s1 += __expf(-fabsf(s_q[1][cc * 4 + 3] - k4.w));
    }
    float c0 = kvc[j * 3 + 0], c1 = kvc[j * 3 + 1], c2 = kvc[j * 3 + 2];
    s0 += __expf(-fabsf(s_qc[0][0] - c0)) * s_wd[0]
        + __expf(-fabsf(s_qc[0][1] - c1)) * s_wd[1]
        + __expf(-fabsf(s_qc[0][2] - c2)) * s_wd[2];
    s1 += __expf(-fabsf(s_qc[1][0] - c0)) * s_wd[0]
        + __expf(-fabsf(s_qc[1][1] - c1)) * s_wd[1]
        + __expf(-fabsf(s_qc[1][2] - c2)) * s_wd[2];
    s0 *= scale; s1 *= scale;
    s_score[0][j] = s0; s_score[1][j] = s1;
    lmax0 = fmaxf(lmax0, s0); lmax1 = fmaxf(lmax1, s1);
  }

  // ---- block-reduce max (both queries) ----
  s_red[0][tid] = lmax0; s_red[1][tid] = lmax1;
  __syncthreads();
  for (int off = 128; off > 0; off >>= 1) {
    if (tid < off) {
      s_red[0][tid] = fmaxf(s_red[0][tid], s_red[0][tid + off]);
      s_red[1][tid] = fmaxf(s_red[1][tid], s_red[1][tid + off]);
    }
    __syncthreads();
  }
  const float m0 = s_red[0][0], m1 = s_red[1][0];
  __syncthreads();

  // ---- exp + sum ----
  float ls0 = 0.f, ls1 = 0.f;
  for (int j = tid; j < NKV; j += 256) {
    float p0 = __expf(s_score[0][j] - m0); s_score[0][j] = p0; ls0 += p0;
    float p1 = __expf(s_score[1][j] - m1); s_score[1][j] = p1; ls1 += p1;
  }
  s_red[0][tid] = ls0; s_red[1][tid] = ls1;
  __syncthreads();
  for (int off = 128; off > 0; off >>= 1) {
    if (tid < off) {
      s_red[0][tid] += s_red[0][tid + off];
      s_red[1][tid] += s_red[1][tid + off];
    }
    __syncthreads();
  }
  const float inv0 = 1.0f / s_red[0][0], inv1 = 1.0f / s_red[1][0];
  __syncthreads();

  // ---- phase 2: out[c] = sum_j p_j * v[j,c] (v load shared by both) ----
  const int c = tid & 63, g = tid >> 6;
  float a0 = 0.f, a1 = 0.f;
  for (int j = g; j < NKV; j += 4) {
    float v = kvp[(size_t)j * 128 + 64 + c];
    a0 = fmaf(s_score[0][j], v, a0);
    a1 = fmaf(s_score[1][j], v, a1);
  }
  s_red[0][tid] = a0; s_red[1][tid] = a1;
  __syncthreads();
  if (g == 0) {
    s_out[0][c] = (s_red[0][c] + s_red[0][64 + c] + s_red[0][128 + c] + s_red[0][192 + c]) * inv0;
    s_out[1][c] = (s_red[1][c] + s_red[1][64 + c] + s_red[1][128 + c] + s_red[1][192 + c]) * inv1;
  }
  __syncthreads();

  // ---- phase 3: projection (both queries) ----
  float p0 = 0.f, p1 = 0.f;
#pragma unroll
  for (int r0 = 0; r0 < 16; ++r0) {
    int r = g * 16 + r0;
    float w = Wproj[r * CH + c];
    p0 = fmaf(s_out[0][r], w, p0);
    p1 = fmaf(s_out[1][r], w, p1);
  }
  s_red[0][tid] = p0; s_red[1][tid] = p1;
  __syncthreads();
  if (g == 0) {
    out[i0 * CH + c] =
        s_red[0][c] + s_red[0][64 + c] + s_red[0][128 + c] + s_red[0][192 + c] + bproj[c];
    out[(i0 + 1) * CH + c] =
        s_red[1][c] + s_red[1][64 + c] + s_red[1][128 + c] + s_red[1][192 + c] + bproj[c];
  }
}

// ---------------------------------------------------------------------------
extern "C" void kernel_launch(void* const* d_in, const int* in_sizes, int n_in,
                              void* d_out, int out_size, void* d_ws, size_t ws_size,
                              hipStream_t stream) {
  const float* q      = (const float*)d_in[0];
  const float* qc     = (const float*)d_in[1];
  const float* kv     = (const float*)d_in[2];
  const float* kvc    = (const float*)d_in[3];
  const float* Wq     = (const float*)d_in[4];
  const float* Wkv    = (const float*)d_in[5];
  const float* Wdelta = (const float*)d_in[6];
  const float* Wproj  = (const float*)d_in[7];
  const float* bproj  = (const float*)d_in[8];
  float* outp = (float*)d_out;

  float* qp  = (float*)d_ws;                 // 512*64 floats
  float* kvp = qp + NQ * CH;                 // 2562*128 floats

  const int total = NQ * CH + NKV * 2 * CH;  // 360704
  gemm_qkv<<<(total + 255) / 256, 256, 0, stream>>>(q, kv, Wq, Wkv, qp, kvp);
  attn_kernel<<<NQ / QB, 256, 0, stream>>>(qp, kvp, qc, kvc, Wdelta, Wproj, bproj, outp);
}

// Round 3
// 158.389 us; speedup vs baseline: 1.6652x; 1.6652x over previous
//
#include <hip/hip_runtime.h>

// Problem constants (B=1)
#define NQ   512
#define NKV  2562
#define CH   64
#define QB   2           // queries per block
#define BT   1024        // attn block threads (16 waves -> 16 waves/CU at 1 block/CU)

// ---------------------------------------------------------------------------
// Kernel A: q_ = q @ Wq   [512,64],  kv_ = kv @ Wkv  [2562,128]
// ---------------------------------------------------------------------------
__global__ __launch_bounds__(256) void gemm_qkv(
    const float* __restrict__ q, const float* __restrict__ kv,
    const float* __restrict__ Wq, const float* __restrict__ Wkv,
    float* __restrict__ qp, float* __restrict__ kvp) {
  int t = blockIdx.x * 256 + threadIdx.x;
  const int NQC = NQ * CH;          // 32768
  const int NKV2C = NKV * 2 * CH;   // 327936
  if (t < NQC) {
    int i = t >> 6, c = t & 63;
    const float* qrow = q + i * CH;
    float s = 0.f;
#pragma unroll
    for (int r = 0; r < CH; ++r) s = fmaf(qrow[r], Wq[r * CH + c], s);
    qp[t] = s;
  } else if (t < NQC + NKV2C) {
    int u = t - NQC;
    int n = u >> 7, m = u & 127;
    const float* kvrow = kv + n * CH;
    float s = 0.f;
#pragma unroll
    for (int r = 0; r < CH; ++r) s = fmaf(kvrow[r], Wkv[r * 2 * CH + m], s);
    kvp[u] = s;
  }
}

// ---------------------------------------------------------------------------
// Kernel B: block = QB=2 query rows, 1024 threads (16 waves).
// ---------------------------------------------------------------------------
__global__ __launch_bounds__(BT) void attn_kernel(
    const float* __restrict__ qp, const float* __restrict__ kvp,
    const float* __restrict__ qc, const float* __restrict__ kvc,
    const float* __restrict__ Wdelta, const float* __restrict__ Wproj,
    const float* __restrict__ bproj, float* __restrict__ out) {
  __shared__ float s_score[QB][NKV];   // 20496 B
  __shared__ float s_q[QB][CH];
  __shared__ float s_qc[QB][3];
  __shared__ float s_wd[3];
  __shared__ float s_red[QB][BT];      // 8192 B
  __shared__ float s_out[QB][CH];

  const int i0 = blockIdx.x * QB;
  const int tid = threadIdx.x;

  if (tid < CH) {
    s_q[0][tid] = qp[i0 * CH + tid];
    s_q[1][tid] = qp[(i0 + 1) * CH + tid];
  }
  if (tid >= 64 && tid < 64 + 3 * QB) {
    int u = tid - 64;
    s_qc[u / 3][u % 3] = qc[(i0 + u / 3) * 3 + (u % 3)];
  }
  if (tid >= 128 && tid < 131) {
    int d = tid - 128;
    float s = 0.f;
    for (int c = 0; c < CH; ++c) s += Wdelta[d * CH + c];
    s_wd[d] = s;
  }
  __syncthreads();

  const float scale = 1.0f / 64.0f;

  // ---- phase 1: scores for both queries ----
  float lmax0 = -1e30f, lmax1 = -1e30f;
  for (int j = tid; j < NKV; j += BT) {
    const float4* krow = reinterpret_cast<const float4*>(kvp + (size_t)j * 128);
    float s0 = 0.f, s1 = 0.f;
#pragma unroll
    for (int cc = 0; cc < 16; ++cc) {
      float4 k4 = krow[cc];
      s0 += __expf(-fabsf(s_q[0][cc * 4 + 0] - k4.x));
      s0 += __expf(-fabsf(s_q[0][cc * 4 + 1] - k4.y));
      s0 += __expf(-fabsf(s_q[0][cc * 4 + 2] - k4.z));
      s0 += __expf(-fabsf(s_q[0][cc * 4 + 3] - k4.w));
      s1 += __expf(-fabsf(s_q[1][cc * 4 + 0] - k4.x));
      s1 += __expf(-fabsf(s_q[1][cc * 4 + 1] - k4.y));
      s1 += __expf(-fabsf(s_q[1][cc * 4 + 2] - k4.z));
      s1 += __expf(-fabsf(s_q[1][cc * 4 + 3] - k4.w));
    }
    float c0 = kvc[j * 3 + 0], c1 = kvc[j * 3 + 1], c2 = kvc[j * 3 + 2];
    s0 += __expf(-fabsf(s_qc[0][0] - c0)) * s_wd[0]
        + __expf(-fabsf(s_qc[0][1] - c1)) * s_wd[1]
        + __expf(-fabsf(s_qc[0][2] - c2)) * s_wd[2];
    s1 += __expf(-fabsf(s_qc[1][0] - c0)) * s_wd[0]
        + __expf(-fabsf(s_qc[1][1] - c1)) * s_wd[1]
        + __expf(-fabsf(s_qc[1][2] - c2)) * s_wd[2];
    s0 *= scale; s1 *= scale;
    s_score[0][j] = s0; s_score[1][j] = s1;
    lmax0 = fmaxf(lmax0, s0); lmax1 = fmaxf(lmax1, s1);
  }

  // ---- block-reduce max ----
  s_red[0][tid] = lmax0; s_red[1][tid] = lmax1;
  __syncthreads();
  for (int off = BT / 2; off > 0; off >>= 1) {
    if (tid < off) {
      s_red[0][tid] = fmaxf(s_red[0][tid], s_red[0][tid + off]);
      s_red[1][tid] = fmaxf(s_red[1][tid], s_red[1][tid + off]);
    }
    __syncthreads();
  }
  const float m0 = s_red[0][0], m1 = s_red[1][0];
  __syncthreads();

  // ---- exp + sum ----
  float ls0 = 0.f, ls1 = 0.f;
  for (int j = tid; j < NKV; j += BT) {
    float p0 = __expf(s_score[0][j] - m0); s_score[0][j] = p0; ls0 += p0;
    float p1 = __expf(s_score[1][j] - m1); s_score[1][j] = p1; ls1 += p1;
  }
  s_red[0][tid] = ls0; s_red[1][tid] = ls1;
  __syncthreads();
  for (int off = BT / 2; off > 0; off >>= 1) {
    if (tid < off) {
      s_red[0][tid] += s_red[0][tid + off];
      s_red[1][tid] += s_red[1][tid + off];
    }
    __syncthreads();
  }
  const float inv0 = 1.0f / s_red[0][0], inv1 = 1.0f / s_red[1][0];
  __syncthreads();

  // ---- phase 2: out[c] = sum_j p_j * v[j,c], 16 j-groups ----
  const int c = tid & 63, g = tid >> 6;           // g in [0,16)
  float a0 = 0.f, a1 = 0.f;
  for (int j = g; j < NKV; j += 16) {
    float v = kvp[(size_t)j * 128 + 64 + c];
    a0 = fmaf(s_score[0][j], v, a0);
    a1 = fmaf(s_score[1][j], v, a1);
  }
  s_red[0][tid] = a0; s_red[1][tid] = a1;
  __syncthreads();
  if (g == 0) {
    float t0 = 0.f, t1 = 0.f;
#pragma unroll
    for (int gg = 0; gg < 16; ++gg) {
      t0 += s_red[0][gg * 64 + c];
      t1 += s_red[1][gg * 64 + c];
    }
    s_out[0][c] = t0 * inv0;
    s_out[1][c] = t1 * inv1;
  }
  __syncthreads();

  // ---- phase 3: projection (16 groups x 4 rows each) ----
  float p0 = 0.f, p1 = 0.f;
#pragma unroll
  for (int r0 = 0; r0 < 4; ++r0) {
    int r = g * 4 + r0;
    float w = Wproj[r * CH + c];
    p0 = fmaf(s_out[0][r], w, p0);
    p1 = fmaf(s_out[1][r], w, p1);
  }
  s_red[0][tid] = p0; s_red[1][tid] = p1;
  __syncthreads();
  if (g == 0) {
    float t0 = 0.f, t1 = 0.f;
#pragma unroll
    for (int gg = 0; gg < 16; ++gg) {
      t0 += s_red[0][gg * 64 + c];
      t1 += s_red[1][gg * 64 + c];
    }
    out[i0 * CH + c] = t0 + bproj[c];
    out[(i0 + 1) * CH + c] = t1 + bproj[c];
  }
}

// ---------------------------------------------------------------------------
extern "C" void kernel_launch(void* const* d_in, const int* in_sizes, int n_in,
                              void* d_out, int out_size, void* d_ws, size_t ws_size,
                              hipStream_t stream) {
  const float* q      = (const float*)d_in[0];
  const float* qc     = (const float*)d_in[1];
  const float* kv     = (const float*)d_in[2];
  const float* kvc    = (const float*)d_in[3];
  const float* Wq     = (const float*)d_in[4];
  const float* Wkv    = (const float*)d_in[5];
  const float* Wdelta = (const float*)d_in[6];
  const float* Wproj  = (const float*)d_in[7];
  const float* bproj  = (const float*)d_in[8];
  float* outp = (float*)d_out;

  float* qp  = (float*)d_ws;                 // 512*64 floats
  float* kvp = qp + NQ * CH;                 // 2562*128 floats

  const int total = NQ * CH + NKV * 2 * CH;  // 360704
  gemm_qkv<<<(total + 255) / 256, 256, 0, stream>>>(q, kv, Wq, Wkv, qp, kvp);
  attn_kernel<<<NQ / QB, BT, 0, stream>>>(qp, kvp, qc, kvc, Wdelta, Wproj, bproj, outp);
}

// Round 4
// 137.089 us; speedup vs baseline: 1.9239x; 1.1554x over previous
//
#include <hip/hip_runtime.h>

// Problem constants (B=1)
#define NQ   512
#define NKV  2562
#define CH   64
#define QB   2           // queries per attn block
#define BT   1024        // attn block threads (16 waves)

// gemm grid partition
#define KVROWS 8
#define NKVB ((NKV + KVROWS - 1) / KVROWS)   // 321
#define QROWS 16
#define NQB (NQ / QROWS)                     // 32

// ---------------------------------------------------------------------------
// Kernel A: q_ = q @ Wq [512,64], kv_ = kv @ Wkv [2562,128].
// LDS-staged input rows, float4 weight loads (W is 16-32KB, L1/L2-resident),
// 4 outputs per thread -> ~16x fewer VMEM insts/output than round-3 version.
// ---------------------------------------------------------------------------
__global__ __launch_bounds__(256) void gemm_qkv(
    const float* __restrict__ q, const float* __restrict__ kv,
    const float* __restrict__ Wq, const float* __restrict__ Wkv,
    float* __restrict__ qp, float* __restrict__ kvp) {
  const int tid = threadIdx.x;
  if (blockIdx.x < NKVB) {
    const int j0 = blockIdx.x * KVROWS;
    __shared__ float s_in[KVROWS][CH];           // 2 KB
    if (tid < KVROWS * (CH / 4)) {               // 128 threads stage via float4
      int r = tid >> 4, g = tid & 15;
      int j = j0 + r;
      float4 v = (j < NKV) ? ((const float4*)(kv + (size_t)j * CH))[g]
                           : make_float4(0.f, 0.f, 0.f, 0.f);
      ((float4*)&s_in[r][0])[g] = v;
    }
    __syncthreads();
    const int r = tid >> 5;                      // 8 rows
    const int mg = (tid & 31) * 4;               // 128 cols / 4
    float4 acc = make_float4(0.f, 0.f, 0.f, 0.f);
#pragma unroll 16
    for (int rr = 0; rr < CH; ++rr) {
      float a = s_in[r][rr];
      float4 w = *(const float4*)(Wkv + (size_t)rr * 2 * CH + mg);
      acc.x = fmaf(a, w.x, acc.x); acc.y = fmaf(a, w.y, acc.y);
      acc.z = fmaf(a, w.z, acc.z); acc.w = fmaf(a, w.w, acc.w);
    }
    int j = j0 + r;
    if (j < NKV) *(float4*)(kvp + (size_t)j * 2 * CH + mg) = acc;
  } else {
    const int i0 = (blockIdx.x - NKVB) * QROWS;
    __shared__ float s_in[QROWS][CH];            // 4 KB
    {
      int r = tid >> 4, g = tid & 15;            // 256 threads = 16 rows x 16 float4
      float4 v = ((const float4*)(q + (size_t)(i0 + r) * CH))[g];
      ((float4*)&s_in[r][0])[g] = v;
    }
    __syncthreads();
    const int r = tid >> 4;                      // 16 rows
    const int cg = (tid & 15) * 4;               // 64 cols / 4
    float4 acc = make_float4(0.f, 0.f, 0.f, 0.f);
#pragma unroll 16
    for (int rr = 0; rr < CH; ++rr) {
      float a = s_in[r][rr];
      float4 w = *(const float4*)(Wq + (size_t)rr * CH + cg);
      acc.x = fmaf(a, w.x, acc.x); acc.y = fmaf(a, w.y, acc.y);
      acc.z = fmaf(a, w.z, acc.z); acc.w = fmaf(a, w.w, acc.w);
    }
    *(float4*)(qp + (size_t)(i0 + r) * CH + cg) = acc;
  }
}

// ---------------------------------------------------------------------------
// Kernel B: block = QB=2 query rows, 1024 threads (16 waves), grid 256.
// Channel-split 4-way: thread = (row j = tid>>2, channels [16*(tid&3), +16)).
// q held in registers (no LDS reads in hot loop); partial scores combined by
// two __shfl_xor within each 4-lane group; sub==0 adds pos term and stores.
// ---------------------------------------------------------------------------
__global__ __launch_bounds__(BT) void attn_kernel(
    const float* __restrict__ qp, const float* __restrict__ kvp,
    const float* __restrict__ qc, const float* __restrict__ kvc,
    const float* __restrict__ Wdelta, const float* __restrict__ Wproj,
    const float* __restrict__ bproj, float* __restrict__ out) {
  __shared__ float s_score[QB][NKV];   // 20496 B
  __shared__ float s_red[QB][BT];      // 8192 B
  __shared__ float s_out[QB][CH];
  __shared__ float s_wd[3];

  const int i0 = blockIdx.x * QB;
  const int tid = threadIdx.x;
  const int sub = tid & 3;
  const int c0 = sub * 16;

  if (tid < 3) {
    float s = 0.f;
    for (int c = 0; c < CH; ++c) s += Wdelta[tid * CH + c];
    s_wd[tid] = s;
  }

  // q slice into registers: 16 floats per query
  float q0[16], q1[16];
  {
    const float4* q0p = (const float4*)(qp + (size_t)i0 * CH + c0);
    const float4* q1p = (const float4*)(qp + (size_t)(i0 + 1) * CH + c0);
#pragma unroll
    for (int g = 0; g < 4; ++g) {
      float4 a = q0p[g];
      q0[4 * g + 0] = a.x; q0[4 * g + 1] = a.y; q0[4 * g + 2] = a.z; q0[4 * g + 3] = a.w;
      float4 b = q1p[g];
      q1[4 * g + 0] = b.x; q1[4 * g + 1] = b.y; q1[4 * g + 2] = b.z; q1[4 * g + 3] = b.w;
    }
  }
  float qc0[3], qc1[3];
#pragma unroll
  for (int d = 0; d < 3; ++d) {
    qc0[d] = qc[(size_t)i0 * 3 + d];
    qc1[d] = qc[(size_t)(i0 + 1) * 3 + d];
  }
  __syncthreads();
  const float wd0 = s_wd[0], wd1 = s_wd[1], wd2 = s_wd[2];

  const float scale = 1.0f / 64.0f;

  // ---- phase 1: scores ----
  float lmax0 = -1e30f, lmax1 = -1e30f;
  for (int j = tid >> 2; j < NKV; j += BT / 4) {
    const float4* kr = (const float4*)(kvp + (size_t)j * 2 * CH + c0);
    float a0 = 0.f, b0 = 0.f, a1 = 0.f, b1 = 0.f;
#pragma unroll
    for (int g = 0; g < 4; ++g) {
      float4 k4 = kr[g];
      a0 += __expf(-fabsf(q0[4 * g + 0] - k4.x));
      b0 += __expf(-fabsf(q0[4 * g + 1] - k4.y));
      a0 += __expf(-fabsf(q0[4 * g + 2] - k4.z));
      b0 += __expf(-fabsf(q0[4 * g + 3] - k4.w));
      a1 += __expf(-fabsf(q1[4 * g + 0] - k4.x));
      b1 += __expf(-fabsf(q1[4 * g + 1] - k4.y));
      a1 += __expf(-fabsf(q1[4 * g + 2] - k4.z));
      b1 += __expf(-fabsf(q1[4 * g + 3] - k4.w));
    }
    float s0 = a0 + b0, s1 = a1 + b1;
    s0 += __shfl_xor(s0, 1); s0 += __shfl_xor(s0, 2);
    s1 += __shfl_xor(s1, 1); s1 += __shfl_xor(s1, 2);
    if (sub == 0) {
      float d0 = kvc[(size_t)j * 3 + 0], d1 = kvc[(size_t)j * 3 + 1], d2 = kvc[(size_t)j * 3 + 2];
      s0 += __expf(-fabsf(qc0[0] - d0)) * wd0
          + __expf(-fabsf(qc0[1] - d1)) * wd1
          + __expf(-fabsf(qc0[2] - d2)) * wd2;
      s1 += __expf(-fabsf(qc1[0] - d0)) * wd0
          + __expf(-fabsf(qc1[1] - d1)) * wd1
          + __expf(-fabsf(qc1[2] - d2)) * wd2;
      s0 *= scale; s1 *= scale;
      s_score[0][j] = s0; s_score[1][j] = s1;
      lmax0 = fmaxf(lmax0, s0); lmax1 = fmaxf(lmax1, s1);
    }
  }

  // ---- block-reduce max ----
  s_red[0][tid] = lmax0; s_red[1][tid] = lmax1;
  __syncthreads();
  for (int off = BT / 2; off > 0; off >>= 1) {
    if (tid < off) {
      s_red[0][tid] = fmaxf(s_red[0][tid], s_red[0][tid + off]);
      s_red[1][tid] = fmaxf(s_red[1][tid], s_red[1][tid + off]);
    }
    __syncthreads();
  }
  const float m0 = s_red[0][0], m1 = s_red[1][0];
  __syncthreads();

  // ---- exp + sum ----
  float ls0 = 0.f, ls1 = 0.f;
  for (int j = tid; j < NKV; j += BT) {
    float p0 = __expf(s_score[0][j] - m0); s_score[0][j] = p0; ls0 += p0;
    float p1 = __expf(s_score[1][j] - m1); s_score[1][j] = p1; ls1 += p1;
  }
  s_red[0][tid] = ls0; s_red[1][tid] = ls1;
  __syncthreads();
  for (int off = BT / 2; off > 0; off >>= 1) {
    if (tid < off) {
      s_red[0][tid] += s_red[0][tid + off];
      s_red[1][tid] += s_red[1][tid + off];
    }
    __syncthreads();
  }
  const float inv0 = 1.0f / s_red[0][0], inv1 = 1.0f / s_red[1][0];
  __syncthreads();

  // ---- phase 2: out[c] = sum_j p_j * v[j,c], 16 j-groups ----
  const int c = tid & 63, g = tid >> 6;           // g in [0,16)
  float a0 = 0.f, a1 = 0.f;
  for (int j = g; j < NKV; j += 16) {
    float v = kvp[(size_t)j * 128 + 64 + c];
    a0 = fmaf(s_score[0][j], v, a0);
    a1 = fmaf(s_score[1][j], v, a1);
  }
  s_red[0][tid] = a0; s_red[1][tid] = a1;
  __syncthreads();
  if (g == 0) {
    float t0 = 0.f, t1 = 0.f;
#pragma unroll
    for (int gg = 0; gg < 16; ++gg) {
      t0 += s_red[0][gg * 64 + c];
      t1 += s_red[1][gg * 64 + c];
    }
    s_out[0][c] = t0 * inv0;
    s_out[1][c] = t1 * inv1;
  }
  __syncthreads();

  // ---- phase 3: projection ----
  float p0 = 0.f, p1 = 0.f;
#pragma unroll
  for (int r0 = 0; r0 < 4; ++r0) {
    int r = g * 4 + r0;
    float w = Wproj[r * CH + c];
    p0 = fmaf(s_out[0][r], w, p0);
    p1 = fmaf(s_out[1][r], w, p1);
  }
  s_red[0][tid] = p0; s_red[1][tid] = p1;
  __syncthreads();
  if (g == 0) {
    float t0 = 0.f, t1 = 0.f;
#pragma unroll
    for (int gg = 0; gg < 16; ++gg) {
      t0 += s_red[0][gg * 64 + c];
      t1 += s_red[1][gg * 64 + c];
    }
    out[i0 * CH + c] = t0 + bproj[c];
    out[(i0 + 1) * CH + c] = t1 + bproj[c];
  }
}

// ---------------------------------------------------------------------------
extern "C" void kernel_launch(void* const* d_in, const int* in_sizes, int n_in,
                              void* d_out, int out_size, void* d_ws, size_t ws_size,
                              hipStream_t stream) {
  const float* q      = (const float*)d_in[0];
  const float* qc     = (const float*)d_in[1];
  const float* kv     = (const float*)d_in[2];
  const float* kvc    = (const float*)d_in[3];
  const float* Wq     = (const float*)d_in[4];
  const float* Wkv    = (const float*)d_in[5];
  const float* Wdelta = (const float*)d_in[6];
  const float* Wproj  = (const float*)d_in[7];
  const float* bproj  = (const float*)d_in[8];
  float* outp = (float*)d_out;

  float* qp  = (float*)d_ws;                 // 512*64 floats
  float* kvp = qp + NQ * CH;                 // 2562*128 floats

  gemm_qkv<<<NKVB + NQB, 256, 0, stream>>>(q, kv, Wq, Wkv, qp, kvp);
  attn_kernel<<<NQ / QB, BT, 0, stream>>>(qp, kvp, qc, kvc, Wdelta, Wproj, bproj, outp);
}

// Round 5
// 110.781 us; speedup vs baseline: 2.3808x; 1.2375x over previous
//
#include <hip/hip_runtime.h>

// Problem constants (B=1)
#define NQ   512
#define NKV  2562
#define CH   64
#define QB   2           // queries per attn block
#define BT   1024        // attn block threads (16 waves, 4/SIMD, 1 block/CU)

// gemm grid partition
#define KVROWS 8
#define NKVB ((NKV + KVROWS - 1) / KVROWS)   // 321
#define QROWS 16
#define NQB (NQ / QROWS)                     // 32

#define E(a, b) __expf(-fabsf((a) - (b)))

// ---------------------------------------------------------------------------
// Kernel A: q_ = q @ Wq [512,64], kv_ = kv @ Wkv [2562,128].
// ---------------------------------------------------------------------------
__global__ __launch_bounds__(256) void gemm_qkv(
    const float* __restrict__ q, const float* __restrict__ kv,
    const float* __restrict__ Wq, const float* __restrict__ Wkv,
    float* __restrict__ qp, float* __restrict__ kvp) {
  const int tid = threadIdx.x;
  if (blockIdx.x < NKVB) {
    const int j0 = blockIdx.x * KVROWS;
    __shared__ float s_in[KVROWS][CH];
    if (tid < KVROWS * (CH / 4)) {
      int r = tid >> 4, g = tid & 15;
      int j = j0 + r;
      float4 v = (j < NKV) ? ((const float4*)(kv + (size_t)j * CH))[g]
                           : make_float4(0.f, 0.f, 0.f, 0.f);
      ((float4*)&s_in[r][0])[g] = v;
    }
    __syncthreads();
    const int r = tid >> 5;
    const int mg = (tid & 31) * 4;
    float4 acc = make_float4(0.f, 0.f, 0.f, 0.f);
#pragma unroll 16
    for (int rr = 0; rr < CH; ++rr) {
      float a = s_in[r][rr];
      float4 w = *(const float4*)(Wkv + (size_t)rr * 2 * CH + mg);
      acc.x = fmaf(a, w.x, acc.x); acc.y = fmaf(a, w.y, acc.y);
      acc.z = fmaf(a, w.z, acc.z); acc.w = fmaf(a, w.w, acc.w);
    }
    int j = j0 + r;
    if (j < NKV) *(float4*)(kvp + (size_t)j * 2 * CH + mg) = acc;
  } else {
    const int i0 = (blockIdx.x - NKVB) * QROWS;
    __shared__ float s_in[QROWS][CH];
    {
      int r = tid >> 4, g = tid & 15;
      float4 v = ((const float4*)(q + (size_t)(i0 + r) * CH))[g];
      ((float4*)&s_in[r][0])[g] = v;
    }
    __syncthreads();
    const int r = tid >> 4;
    const int cg = (tid & 15) * 4;
    float4 acc = make_float4(0.f, 0.f, 0.f, 0.f);
#pragma unroll 16
    for (int rr = 0; rr < CH; ++rr) {
      float a = s_in[r][rr];
      float4 w = *(const float4*)(Wq + (size_t)rr * CH + cg);
      acc.x = fmaf(a, w.x, acc.x); acc.y = fmaf(a, w.y, acc.y);
      acc.z = fmaf(a, w.z, acc.z); acc.w = fmaf(a, w.w, acc.w);
    }
    *(float4*)(qp + (size_t)(i0 + r) * CH + cg) = acc;
  }
}

// ---------------------------------------------------------------------------
// Kernel B: block = QB=2 query rows, 1024 threads (16 waves), grid 256.
// Channel-split 4-way; q slice held in 8 NAMED float4 registers (pinned via
// empty asm so the loads cannot be rematerialized inside the hot loop).
// Softmax reductions: wave shfl_xor + 16-entry cross-wave LDS combine.
// ---------------------------------------------------------------------------
__global__ __launch_bounds__(BT, 4) void attn_kernel(
    const float* __restrict__ qp, const float* __restrict__ kvp,
    const float* __restrict__ qc, const float* __restrict__ kvc,
    const float* __restrict__ Wdelta, const float* __restrict__ Wproj,
    const float* __restrict__ bproj, float* __restrict__ out) {
  __shared__ float s_score[QB][NKV];   // 20496 B
  __shared__ float s_red[QB][BT];      // 8192 B
  __shared__ float s_out[QB][CH];
  __shared__ float s_wd[3];

  const int i0 = blockIdx.x * QB;
  const int tid = threadIdx.x;
  const int sub = tid & 3;
  const int c0 = sub * 16;
  const int wid = tid >> 6;
  const int lane = tid & 63;

  if (tid < 3) {
    float s = 0.f;
    for (int c = 0; c < CH; ++c) s += Wdelta[tid * CH + c];
    s_wd[tid] = s;
  }

  // q slices into named registers
  const float4* q0p = (const float4*)(qp + (size_t)i0 * CH + c0);
  const float4* q1p = (const float4*)(qp + (size_t)(i0 + 1) * CH + c0);
  float4 qa0 = q0p[0], qa1 = q0p[1], qa2 = q0p[2], qa3 = q0p[3];
  float4 qb0 = q1p[0], qb1 = q1p[1], qb2 = q1p[2], qb3 = q1p[3];
  // pin to registers: prevent the compiler from sinking these loads into the loop
  asm volatile("" : "+v"(qa0.x), "+v"(qa0.y), "+v"(qa0.z), "+v"(qa0.w),
                    "+v"(qa1.x), "+v"(qa1.y), "+v"(qa1.z), "+v"(qa1.w),
                    "+v"(qa2.x), "+v"(qa2.y), "+v"(qa2.z), "+v"(qa2.w),
                    "+v"(qa3.x), "+v"(qa3.y), "+v"(qa3.z), "+v"(qa3.w));
  asm volatile("" : "+v"(qb0.x), "+v"(qb0.y), "+v"(qb0.z), "+v"(qb0.w),
                    "+v"(qb1.x), "+v"(qb1.y), "+v"(qb1.z), "+v"(qb1.w),
                    "+v"(qb2.x), "+v"(qb2.y), "+v"(qb2.z), "+v"(qb2.w),
                    "+v"(qb3.x), "+v"(qb3.y), "+v"(qb3.z), "+v"(qb3.w));

  float qc0[3], qc1[3];
#pragma unroll
  for (int d = 0; d < 3; ++d) {
    qc0[d] = qc[(size_t)i0 * 3 + d];
    qc1[d] = qc[(size_t)(i0 + 1) * 3 + d];
  }
  __syncthreads();
  const float wd0 = s_wd[0], wd1 = s_wd[1], wd2 = s_wd[2];
  const float scale = 1.0f / 64.0f;

  // ---- phase 1: scores ----
  float lmax0 = -1e30f, lmax1 = -1e30f;
  for (int j = tid >> 2; j < NKV; j += BT / 4) {
    const float4* kr = (const float4*)(kvp + (size_t)j * 2 * CH + c0);
    float4 k0 = kr[0], k1 = kr[1], k2 = kr[2], k3 = kr[3];
    float s0 = ((E(qa0.x, k0.x) + E(qa0.y, k0.y)) + (E(qa0.z, k0.z) + E(qa0.w, k0.w)))
             + ((E(qa1.x, k1.x) + E(qa1.y, k1.y)) + (E(qa1.z, k1.z) + E(qa1.w, k1.w)))
             + ((E(qa2.x, k2.x) + E(qa2.y, k2.y)) + (E(qa2.z, k2.z) + E(qa2.w, k2.w)))
             + ((E(qa3.x, k3.x) + E(qa3.y, k3.y)) + (E(qa3.z, k3.z) + E(qa3.w, k3.w)));
    float s1 = ((E(qb0.x, k0.x) + E(qb0.y, k0.y)) + (E(qb0.z, k0.z) + E(qb0.w, k0.w)))
             + ((E(qb1.x, k1.x) + E(qb1.y, k1.y)) + (E(qb1.z, k1.z) + E(qb1.w, k1.w)))
             + ((E(qb2.x, k2.x) + E(qb2.y, k2.y)) + (E(qb2.z, k2.z) + E(qb2.w, k2.w)))
             + ((E(qb3.x, k3.x) + E(qb3.y, k3.y)) + (E(qb3.z, k3.z) + E(qb3.w, k3.w)));
    s0 += __shfl_xor(s0, 1); s0 += __shfl_xor(s0, 2);
    s1 += __shfl_xor(s1, 1); s1 += __shfl_xor(s1, 2);
    if (sub == 0) {
      float d0 = kvc[(size_t)j * 3 + 0], d1 = kvc[(size_t)j * 3 + 1], d2 = kvc[(size_t)j * 3 + 2];
      s0 += E(qc0[0], d0) * wd0 + E(qc0[1], d1) * wd1 + E(qc0[2], d2) * wd2;
      s1 += E(qc1[0], d0) * wd0 + E(qc1[1], d1) * wd1 + E(qc1[2], d2) * wd2;
      s0 *= scale; s1 *= scale;
      s_score[0][j] = s0; s_score[1][j] = s1;
      lmax0 = fmaxf(lmax0, s0); lmax1 = fmaxf(lmax1, s1);
    }
  }

  // ---- max: wave shfl reduce + cross-wave combine ----
#pragma unroll
  for (int off = 1; off < 64; off <<= 1) {
    lmax0 = fmaxf(lmax0, __shfl_xor(lmax0, off));
    lmax1 = fmaxf(lmax1, __shfl_xor(lmax1, off));
  }
  if (lane == 0) { s_red[0][wid] = lmax0; s_red[1][wid] = lmax1; }
  __syncthreads();
  float m0 = s_red[0][0], m1 = s_red[1][0];
#pragma unroll
  for (int w = 1; w < BT / 64; ++w) {
    m0 = fmaxf(m0, s_red[0][w]);
    m1 = fmaxf(m1, s_red[1][w]);
  }
  __syncthreads();   // everyone done reading s_red before reuse

  // ---- exp + sum ----
  float ls0 = 0.f, ls1 = 0.f;
  for (int j = tid; j < NKV; j += BT) {
    float p0 = __expf(s_score[0][j] - m0); s_score[0][j] = p0; ls0 += p0;
    float p1 = __expf(s_score[1][j] - m1); s_score[1][j] = p1; ls1 += p1;
  }
#pragma unroll
  for (int off = 1; off < 64; off <<= 1) {
    ls0 += __shfl_xor(ls0, off);
    ls1 += __shfl_xor(ls1, off);
  }
  if (lane == 0) { s_red[0][wid] = ls0; s_red[1][wid] = ls1; }
  __syncthreads();
  float t0 = s_red[0][0], t1 = s_red[1][0];
#pragma unroll
  for (int w = 1; w < BT / 64; ++w) { t0 += s_red[0][w]; t1 += s_red[1][w]; }
  const float inv0 = 1.0f / t0, inv1 = 1.0f / t1;
  __syncthreads();   // before s_red reuse in phase 2

  // ---- phase 2: out[c] = sum_j p_j * v[j,c], wave g handles j = g + 16k ----
  const int c = tid & 63, g = tid >> 6;
  float a0 = 0.f, a1 = 0.f;
#pragma unroll 4
  for (int j = g; j < NKV; j += 16) {
    float v = kvp[(size_t)j * 128 + 64 + c];
    a0 = fmaf(s_score[0][j], v, a0);
    a1 = fmaf(s_score[1][j], v, a1);
  }
  s_red[0][tid] = a0; s_red[1][tid] = a1;
  __syncthreads();
  if (g == 0) {
    float u0 = 0.f, u1 = 0.f;
#pragma unroll
    for (int gg = 0; gg < 16; ++gg) {
      u0 += s_red[0][gg * 64 + c];
      u1 += s_red[1][gg * 64 + c];
    }
    s_out[0][c] = u0 * inv0;
    s_out[1][c] = u1 * inv1;
  }
  __syncthreads();

  // ---- phase 3: projection ----
  float p0 = 0.f, p1 = 0.f;
#pragma unroll
  for (int r0 = 0; r0 < 4; ++r0) {
    int r = g * 4 + r0;
    float w = Wproj[r * CH + c];
    p0 = fmaf(s_out[0][r], w, p0);
    p1 = fmaf(s_out[1][r], w, p1);
  }
  s_red[0][tid] = p0; s_red[1][tid] = p1;
  __syncthreads();
  if (g == 0) {
    float u0 = 0.f, u1 = 0.f;
#pragma unroll
    for (int gg = 0; gg < 16; ++gg) {
      u0 += s_red[0][gg * 64 + c];
      u1 += s_red[1][gg * 64 + c];
    }
    out[i0 * CH + c] = u0 + bproj[c];
    out[(i0 + 1) * CH + c] = u1 + bproj[c];
  }
}

// ---------------------------------------------------------------------------
extern "C" void kernel_launch(void* const* d_in, const int* in_sizes, int n_in,
                              void* d_out, int out_size, void* d_ws, size_t ws_size,
                              hipStream_t stream) {
  const float* q      = (const float*)d_in[0];
  const float* qc     = (const float*)d_in[1];
  const float* kv     = (const float*)d_in[2];
  const float* kvc    = (const float*)d_in[3];
  const float* Wq     = (const float*)d_in[4];
  const float* Wkv    = (const float*)d_in[5];
  const float* Wdelta = (const float*)d_in[6];
  const float* Wproj  = (const float*)d_in[7];
  const float* bproj  = (const float*)d_in[8];
  float* outp = (float*)d_out;

  float* qp  = (float*)d_ws;                 // 512*64 floats
  float* kvp = qp + NQ * CH;                 // 2562*128 floats

  gemm_qkv<<<NKVB + NQB, 256, 0, stream>>>(q, kv, Wq, Wkv, qp, kvp);
  attn_kernel<<<NQ / QB, BT, 0, stream>>>(qp, kvp, qc, kvc, Wdelta, Wproj, bproj, outp);
}